// Round 1
// 151.553 us; speedup vs baseline: 1.0708x; 1.0708x over previous
//
#include <hip/hip_runtime.h>
#include <math.h>

#define NB 8
#define NC 256
#define NL 4096
#define NK 65

// Per-batch stats. [b][0..3] = sum_re, sum_im, sum_sq, (spare)
__device__ float g_stats[NB * 4];

__global__ void zero_stats_kernel() {
    if (threadIdx.x < NB * 4) g_stats[threadIdx.x] = 0.0f;
}

// ---------------------------------------------------------------------------
// Fused: conv (direct per-row global loads, register sliding window, NO
// staging barriers) + pre-weight stats + weight (inv_std deferred by
// linearity to scale pass) + 256-pt radix-4 FFT over channels + fftshift +
// store. x is XCD-L2-resident (b = bid&7 swizzle: one batch == 4 MB == one
// XCD L2), and each LOAD16 is exactly one 64B line per lane, so the
// global->LDS->reg staging round-trip (and its 10 barriers) is pure
// overhead -- removed.
// Block = one 16-wide l-tile, thread = channel.
// ---------------------------------------------------------------------------

#define LOAD16(W, off)                                                      \
    {                                                                       \
        const int g0_ = l0 + (off);                                         \
        if (g0_ >= 0 && g0_ + 16 <= NL) {  /* block-uniform branch */       \
            _Pragma("unroll")                                               \
            for (int q = 0; q < 4; ++q) {                                   \
                const float4 v_ = *(const float4*)(xr + g0_ + 4 * q);       \
                W[4*q+0] = v_.x; W[4*q+1] = v_.y;                           \
                W[4*q+2] = v_.z; W[4*q+3] = v_.w;                           \
            }                                                               \
        } else {                                                            \
            _Pragma("unroll")                                               \
            for (int q = 0; q < 16; ++q) {                                  \
                const int g_ = g0_ + q;                                     \
                W[q] = (g_ >= 0 && g_ < NL) ? xr[g_] : 0.0f;                \
            }                                                               \
        }                                                                   \
    }

// taps tb..tb+15 over window Lo[0..15],Hi[0..15] (rel words [tb-32, tb-2])
#define CHUNK16(Lo, Hi, tb)                                                 \
    {                                                                       \
        _Pragma("unroll")                                                   \
        for (int j2 = 0; j2 < 16; ++j2) {                                   \
            const float kr_ = kre[(tb) + j2];   /* uniform -> s_load */     \
            const float ki_ = kim[(tb) + j2];                               \
            _Pragma("unroll")                                               \
            for (int i = 0; i < 16; ++i) {                                  \
                const int wi_ = i + j2;                                     \
                const float xv_ = (wi_ < 16) ? Lo[wi_] : Hi[wi_ - 16];      \
                sr[i] = fmaf(xv_, kr_, sr[i]);                              \
                si[i] = fmaf(xv_, ki_, si[i]);                              \
            }                                                               \
        }                                                                   \
    }

__global__ __launch_bounds__(256) void fused_conv_fft_kernel(
    const float* __restrict__ x,
    const float* __restrict__ kre,
    const float* __restrict__ kim,
    const float* __restrict__ wmag,
    const float* __restrict__ wang,
    float* __restrict__ out,
    int out_size)
{
    __shared__ __align__(16) float4 lbuf4[NC * 9];  // 36 KB: FFT workspace
    __shared__ float twr[NC], twi[NC];
    __shared__ float red[12];

    const int t = threadIdx.x;              // channel
    const int b = blockIdx.x & 7;           // batch == XCD
    const int l0 = (blockIdx.x >> 3) << 4;  // tile base

    {
        float ang = (float)t * 0.024543692606170260f;  // 2*pi/256
        float s, c;
        sincosf(ang, &s, &c);
        twr[t] = c; twi[t] = -s;
    }
    float sw, cw;
    sincosf(wang[t], &sw, &cw);
    const float wm = wmag[t];
    const float wgr =  wm * cw;             // weight WITHOUT inv_std
    const float wgi = -wm * sw;

    const float* xr = x + (size_t)b * NC * NL + (size_t)t * NL;  // own row
    const bool interleaved = (out_size >= 2 * NB * NC * NL);

    float sr[16], si[16];
    #pragma unroll
    for (int i = 0; i < 16; ++i) { sr[i] = 0.0f; si[i] = 0.0f; }

    // ---- conv: 65 taps, register sliding window, no barriers ----
    // window rel word coverage: [l0-32, l0+48)
    float A[16], B[16];
    LOAD16(A, -32);
    LOAD16(B, -16);
    CHUNK16(A, B, 0);        // taps  0..15, words [-32, -2]
    LOAD16(A, 0);
    CHUNK16(B, A, 16);       // taps 16..31, words [-16, 14]
    LOAD16(B, 16);
    CHUNK16(A, B, 32);       // taps 32..47, words [  0, 30]
    LOAD16(A, 32);
    CHUNK16(B, A, 48);       // taps 48..63, words [ 16, 46]
    {   // tail tap j = 64: words rel [32, 47] == A
        const float kr_ = kre[64];
        const float ki_ = kim[64];
        #pragma unroll
        for (int i = 0; i < 16; ++i) {
            sr[i] = fmaf(A[i], kr_, sr[i]);
            si[i] = fmaf(A[i], ki_, si[i]);
        }
    }

    // ---- stats on y = (sr, -si), PRE-weight (un-normalized) ----
    float tsr = 0.0f, tsi = 0.0f, tsq = 0.0f;
    #pragma unroll
    for (int i = 0; i < 16; ++i) {
        tsr += sr[i];
        tsi -= si[i];
        tsq = fmaf(sr[i], sr[i], tsq);
        tsq = fmaf(si[i], si[i], tsq);
    }

    // ---- weight: y' = y * (wgr + i*wgi) -> own FFT row ----
    #pragma unroll
    for (int k = 0; k < 8; ++k) {
        float4 o;
        o.x = sr[2*k]   * wgr + si[2*k]   * wgi;
        o.y = sr[2*k]   * wgi - si[2*k]   * wgr;
        o.z = sr[2*k+1] * wgr + si[2*k+1] * wgi;
        o.w = sr[2*k+1] * wgi - si[2*k+1] * wgr;
        lbuf4[t * 9 + k] = o;
    }
    __syncthreads();   // also covers twr/twi visibility

    // ---- 4 radix-4 DIF stages over channels (row stride 9 float4) ----
    #pragma unroll
    for (int s = 0; s < 4; ++s) {
        const int shift = 2 * s;
        const int q = 64 >> shift;
        #pragma unroll
        for (int it = 0; it < 2; ++it) {
            int task = it * 256 + t;       // 512 tasks = 64 butterflies x 8 lpairs
            int lpp = task & 7;
            int m = task >> 3;
            int j = m & (q - 1);
            int blk = m >> (6 - shift);
            int base2 = blk << (8 - shift);
            int e = j << shift;            // 3e <= 189 < 256

            int ca = base2 + j;
            float4 a0 = lbuf4[ca*9 + lpp];
            float4 a1 = lbuf4[(ca + q)*9 + lpp];
            float4 a2 = lbuf4[(ca + 2*q)*9 + lpp];
            float4 a3 = lbuf4[(ca + 3*q)*9 + lpp];

            float w1r = twr[e],   w1i = twi[e];
            float w2r = twr[2*e], w2i = twi[2*e];
            float w3r = twr[3*e], w3i = twi[3*e];

            float4 b0, b1, b2, b3;
            {
                float t0r = a0.x + a2.x, t0i = a0.y + a2.y;
                float t1r = a0.x - a2.x, t1i = a0.y - a2.y;
                float t2r = a1.x + a3.x, t2i = a1.y + a3.y;
                float t3r = a1.x - a3.x, t3i = a1.y - a3.y;
                b0.x = t0r + t2r;       b0.y = t0i + t2i;
                float b2r = t0r - t2r,  b2i = t0i - t2i;
                float b1r = t1r + t3i,  b1i = t1i - t3r;
                float b3r = t1r - t3i,  b3i = t1i + t3r;
                b1.x = b1r*w1r - b1i*w1i;  b1.y = b1r*w1i + b1i*w1r;
                b2.x = b2r*w2r - b2i*w2i;  b2.y = b2r*w2i + b2i*w2r;
                b3.x = b3r*w3r - b3i*w3i;  b3.y = b3r*w3i + b3i*w3r;
            }
            {
                float t0r = a0.z + a2.z, t0i = a0.w + a2.w;
                float t1r = a0.z - a2.z, t1i = a0.w - a2.w;
                float t2r = a1.z + a3.z, t2i = a1.w + a3.w;
                float t3r = a1.z - a3.z, t3i = a1.w - a3.w;
                b0.z = t0r + t2r;       b0.w = t0i + t2i;
                float b2r = t0r - t2r,  b2i = t0i - t2i;
                float b1r = t1r + t3i,  b1i = t1i - t3r;
                float b3r = t1r - t3i,  b3i = t1i + t3r;
                b1.z = b1r*w1r - b1i*w1i;  b1.w = b1r*w1i + b1i*w1r;
                b2.z = b2r*w2r - b2i*w2i;  b2.w = b2r*w2i + b2i*w2r;
                b3.z = b3r*w3r - b3i*w3i;  b3.w = b3r*w3i + b3i*w3r;
            }
            lbuf4[ca*9 + lpp]         = b0;
            lbuf4[(ca + q)*9 + lpp]   = b1;
            lbuf4[(ca + 2*q)*9 + lpp] = b2;
            lbuf4[(ca + 3*q)*9 + lpp] = b3;
        }
        __syncthreads();
    }

    // ---- store (un-normalized): digit-reverse + fftshift ----
    #pragma unroll
    for (int it = 0; it < 8; ++it) {
        int task = it * 256 + t;
        int lpp = task & 7;
        int pp = task >> 3;
        float4 v = lbuf4[pp*9 + lpp];
        int k = ((pp & 3) << 6) | (((pp >> 2) & 3) << 4)
              | (((pp >> 4) & 3) << 2) | ((pp >> 6) & 3);
        int cout = k ^ 128;  // fftshift
        if (interleaved) {
            size_t fi = 2 * ((size_t)(b * NC + cout) * NL + l0) + 4 * lpp;
            if (fi + 4 <= (size_t)out_size) *(float4*)(out + fi) = v;
        } else {
            size_t fi = (size_t)(b * NC + cout) * NL + l0 + 2 * lpp;
            if (fi + 2 <= (size_t)out_size) {
                float2 o2; o2.x = v.x; o2.y = v.z;
                *(float2*)(out + fi) = o2;
            }
        }
    }

    // ---- block stats -> per-batch atomics ----
    #pragma unroll
    for (int off = 32; off > 0; off >>= 1) {
        tsr += __shfl_down(tsr, off);
        tsi += __shfl_down(tsi, off);
        tsq += __shfl_down(tsq, off);
    }
    const int lane = t & 63, wv = t >> 6;
    if (lane == 0) { red[wv*3+0] = tsr; red[wv*3+1] = tsi; red[wv*3+2] = tsq; }
    __syncthreads();
    if (t == 0) {
        float a0 = 0.0f, a1 = 0.0f, a2 = 0.0f;
        for (int i = 0; i < 4; ++i) { a0 += red[i*3]; a1 += red[i*3+1]; a2 += red[i*3+2]; }
        atomicAdd(&g_stats[b*4+0], a0);
        atomicAdd(&g_stats[b*4+1], a1);
        atomicAdd(&g_stats[b*4+2], a2);
    }
}

// ---------------------------------------------------------------------------
// Finalize (inv_std from raw sums, computed per block -- no separate kernel)
// + out *= inv_std[b]. chunk = out_size/NB is a power of two -> shift.
// ---------------------------------------------------------------------------
__global__ __launch_bounds__(256) void scale_out_kernel(
    float* __restrict__ out, int out_size)
{
    __shared__ float sinv[NB];
    const int t = threadIdx.x;
    if (t < NB) {
        float sr = g_stats[t*4+0], si = g_stats[t*4+1], sq = g_stats[t*4+2];
        const float n = (float)(NC * NL);
        float var = (sq - (sr*sr + si*si)/n) / (n - 1.0f);
        sinv[t] = rsqrtf(var);
    }
    __syncthreads();

    const int chunk = out_size >> 3;            // floats per batch (NB=8)
    const bool p2 = (chunk & (chunk - 1)) == 0;
    const int lb = 31 - __clz(chunk);           // chunk == 1<<lb when p2
    const int n4 = out_size >> 2;
    float4* o4 = (float4*)out;
    for (int i4 = blockIdx.x * blockDim.x + t; i4 < n4;
         i4 += gridDim.x * blockDim.x) {
        int fi = i4 << 2;
        int bidx = p2 ? (fi >> lb) : (fi / chunk);
        float inv = sinv[bidx];
        float4 v = o4[i4];
        v.x *= inv; v.y *= inv; v.z *= inv; v.w *= inv;
        o4[i4] = v;
    }
    int tail0 = n4 << 2;
    int ti = tail0 + blockIdx.x * blockDim.x + t;
    if (ti < out_size) {
        int bidx = p2 ? (ti >> lb) : (ti / chunk);
        out[ti] *= sinv[bidx];
    }
}

extern "C" void kernel_launch(void* const* d_in, const int* in_sizes, int n_in,
                              void* d_out, int out_size, void* d_ws, size_t ws_size,
                              hipStream_t stream)
{
    const float* x   = (const float*)d_in[0];
    const float* kre = (const float*)d_in[1];
    const float* kim = (const float*)d_in[2];
    const float* wm  = (const float*)d_in[3];
    const float* wa  = (const float*)d_in[4];
    float* out = (float*)d_out;
    (void)d_ws; (void)ws_size;

    zero_stats_kernel<<<1, 64, 0, stream>>>();
    fused_conv_fft_kernel<<<NB * (NL / 16), 256, 0, stream>>>(x, kre, kim, wm, wa,
                                                              out, out_size);
    scale_out_kernel<<<2048, 256, 0, stream>>>(out, out_size);
}